// Round 1
// baseline (346.795 us; speedup 1.0000x reference)
//
#include <hip/hip_runtime.h>
#include <hip/hip_bf16.h>
#include <math.h>

#define BB 32
#define NN 128
#define HH 8
#define EE 64
#define CC 16
#define DD 512  // HH*EE

#define NEG_BIG (-1.0e30f)

// ---- bf16 helpers (raw-bit, bf16 -> f32 is a 16-bit shift) ----
__device__ __forceinline__ float bf2f(unsigned short u) {
    union { unsigned int i; float f; } x; x.i = ((unsigned int)u) << 16; return x.f;
}
__device__ __forceinline__ float bflo(unsigned int u) {
    union { unsigned int i; float f; } x; x.i = u << 16; return x.f;
}
__device__ __forceinline__ float bfhi(unsigned int u) {
    union { unsigned int i; float f; } x; x.i = u & 0xffff0000u; return x.f;
}
__device__ __forceinline__ unsigned short f2bf(float f) {
    union { float f; unsigned int i; } x; x.f = f;
    unsigned int r = x.i + 0x7fffu + ((x.i >> 16) & 1u);  // RNE
    return (unsigned short)(r >> 16);
}

template <bool F32>
__device__ __forceinline__ float ldx(const void* p, int i) {
    if constexpr (F32) return ((const float*)p)[i];
    else               return bf2f(((const unsigned short*)p)[i]);
}

// head configs replicated from auto_head_configs(8, 128) (verified by enumeration):
// K = {3,5,3,5,3,5,3,3}, d = {1,5,19,14,37,23,55,63}
__device__ const int g_dil[8] = {1, 5, 19, 14, 37, 23, 55, 63};

// ---------------- dtype detector: writes flag (1 = f32 inputs, 0 = bf16 inputs) ----
__global__ void detect_dtype(const unsigned short* __restrict__ q, int* __restrict__ flag) {
    const int lane = threadIdx.x;  // 64 threads
    int outliers = 0;
    #pragma unroll
    for (int i = 0; i < 16; ++i) {
        unsigned short u = q[(i * 64 + lane) * 2];
        int e = (u >> 7) & 0xFF;
        int sane = (e >= 101 && e <= 140) || ((u & 0x7FFFu) == 0);
        outliers += !sane;
    }
    #pragma unroll
    for (int m = 32; m >= 1; m >>= 1) outliers += __shfl_xor(outliers, m, 64);
    if (lane == 0) *flag = (outliers > 256) ? 1 : 0;
}

// ---------------- Kernel A: gate = sigmoid(gelu(mean_n(V) @ w1 + b1) @ w2 + b2) ----
template <bool F32>
__global__ __launch_bounds__(256) void gate_kernel(
    const void* __restrict__ values,  // [B,C,N,D]
    const void* __restrict__ w1,      // [D, D/4]
    const void* __restrict__ b1,      // [D/4]
    const void* __restrict__ w2,      // [D/4]
    const void* __restrict__ b2,      // [1]
    const int*  __restrict__ flag,
    float* __restrict__ gate_out)     // [B*C] f32
{
    if (*flag != (F32 ? 1 : 0)) return;
    __shared__ float vp[DD];
    __shared__ float hid[DD / 4];
    const int bc = blockIdx.x;       // b*C + c
    const int t  = threadIdx.x;      // 0..255, each owns 2 adjacent d-columns
    float a0 = 0.f, a1 = 0.f;
    if constexpr (F32) {
        const float2* vb = (const float2*)((const float*)values + (size_t)bc * NN * DD);
        #pragma unroll 4
        for (int n = 0; n < NN; ++n) { float2 u = vb[n * (DD / 2) + t]; a0 += u.x; a1 += u.y; }
    } else {
        const unsigned int* vb = (const unsigned int*)((const unsigned short*)values + (size_t)bc * NN * DD);
        #pragma unroll 4
        for (int n = 0; n < NN; ++n) { unsigned int u = vb[n * (DD / 2) + t]; a0 += bflo(u); a1 += bfhi(u); }
    }
    vp[2 * t]     = a0 * (1.0f / NN);
    vp[2 * t + 1] = a1 * (1.0f / NN);
    __syncthreads();
    if (t < DD / 4) {
        float a = ldx<F32>(b1, t);
        for (int dd = 0; dd < DD; ++dd)
            a += vp[dd] * ldx<F32>(w1, dd * (DD / 4) + t);
        hid[t] = 0.5f * a * (1.0f + erff(a * 0.70710678118654752440f));  // exact gelu
    }
    __syncthreads();
    if (t < 64) {
        float s = hid[t] * ldx<F32>(w2, t) + hid[t + 64] * ldx<F32>(w2, t + 64);
        #pragma unroll
        for (int m = 32; m >= 1; m >>= 1) s += __shfl_xor(s, m, 64);
        if (t == 0) {
            float z = s + ldx<F32>(b2, 0);
            gate_out[bc] = 1.0f / (1.0f + expf(-z));
        }
    }
}

// ---------------- Kernel B: sparse neighborhood attention, 1 wave per (b,h,n) ----
// Score phase restructured: 4 lanes per (c,k) pair instead of 1 lane per pair.
//   group g = lane>>2 -> exo-var c (16 groups = CC), sub = lane&3 -> 16-dim E slice.
//   Pair index is k*CC + c, so each k-pass has wave-uniform j (no divergence) and
//   every load instruction touches 16 rows x 64 contiguous bytes (vs 64 x 16B before).
template <bool F32>
__global__ __launch_bounds__(256) void attn_kernel(
    const void* __restrict__ qptr,  // [B,N,H,E]
    const void* __restrict__ kptr,  // [B,C,N,H,E]
    const void* __restrict__ vptr,  // [B,C,N,H,E]
    const float* __restrict__ gate, // [B*C]
    const int*  __restrict__ flag,
    void* __restrict__ optr)        // [B,N,H,E]
{
    if (*flag != (F32 ? 1 : 0)) return;
    __shared__ float lds_w[4][CC * 5];   // raw scores, then normalized gated weights
    const int tid  = threadIdx.x;
    const int wave = tid >> 6;
    const int lane = tid & 63;

    // XCD-locality swizzle: phys block p -> XCD p%8 (round-robin assumption).
    // virt = ((p&7)<<10)|(p>>3) gives each XCD a contiguous range of (b,h) groups
    // so the ~1MB per-(b,h) key/value working set stays L2-resident.
    const int p    = blockIdx.x;
    const int virt = ((p & 7) << 10) | (p >> 3);
    const int gw   = virt * 4 + wave;       // (b*H + h)*N + n
    const int n = gw & (NN - 1);
    const int h = (gw >> 7) & (HH - 1);
    const int b = gw >> 10;
    const int K   = ((h & 1) && (h != 7)) ? 5 : 3;
    const int dil = g_dil[h];
    const int nb  = CC * K;                 // 48 or 80 candidate pairs

    const int g   = lane >> 2;              // exo-var c owned by this 4-lane group
    const int sub = lane & 3;               // 16-dim slice of E

    const size_t qoff  = (((size_t)b * NN + n) * HH + h) * EE;
    const size_t kvoff = ((size_t)b * CC * NN) * DD + (size_t)h * EE;

    // q slice (16 dims) into registers, scale folded in
    float qreg[16];
    if constexpr (F32) {
        const float4* qp = (const float4*)((const float*)qptr + qoff + sub * 16);
        #pragma unroll
        for (int i = 0; i < 4; ++i) {
            float4 u = qp[i];
            qreg[4 * i + 0] = u.x * 0.125f; qreg[4 * i + 1] = u.y * 0.125f;
            qreg[4 * i + 2] = u.z * 0.125f; qreg[4 * i + 3] = u.w * 0.125f;
        }
    } else {
        const uint4* qp = (const uint4*)((const unsigned short*)qptr + qoff + sub * 16);
        #pragma unroll
        for (int i = 0; i < 2; ++i) {
            uint4 u = qp[i];
            qreg[8 * i + 0] = bflo(u.x) * 0.125f; qreg[8 * i + 1] = bfhi(u.x) * 0.125f;
            qreg[8 * i + 2] = bflo(u.y) * 0.125f; qreg[8 * i + 3] = bfhi(u.y) * 0.125f;
            qreg[8 * i + 4] = bflo(u.z) * 0.125f; qreg[8 * i + 5] = bfhi(u.z) * 0.125f;
            qreg[8 * i + 6] = bflo(u.w) * 0.125f; qreg[8 * i + 7] = bfhi(u.w) * 0.125f;
        }
    }

    // ---- scores: pass k covers all 16 exo vars at wave-uniform j ----
    const size_t rowbase = kvoff + (size_t)g * NN * DD + (size_t)sub * 16;
    for (int k = 0; k < K; ++k) {
        int j = n + (k - (K >> 1)) * dil;
        float s = NEG_BIG;
        if (j >= 0 && j < NN) {              // wave-uniform branch
            size_t off = rowbase + (size_t)j * DD;
            float a0 = 0.f, a1 = 0.f, a2 = 0.f, a3 = 0.f;
            if constexpr (F32) {
                const float4* kp = (const float4*)((const float*)kptr + off);
                #pragma unroll
                for (int i = 0; i < 4; ++i) {
                    float4 kk = kp[i];
                    a0 += qreg[4 * i + 0] * kk.x; a1 += qreg[4 * i + 1] * kk.y;
                    a2 += qreg[4 * i + 2] * kk.z; a3 += qreg[4 * i + 3] * kk.w;
                }
            } else {
                const uint4* kp = (const uint4*)((const unsigned short*)kptr + off);
                #pragma unroll
                for (int i = 0; i < 2; ++i) {
                    uint4 kk = kp[i];
                    a0 += qreg[8 * i + 0] * bflo(kk.x); a1 += qreg[8 * i + 1] * bfhi(kk.x);
                    a2 += qreg[8 * i + 2] * bflo(kk.y); a3 += qreg[8 * i + 3] * bfhi(kk.y);
                    a0 += qreg[8 * i + 4] * bflo(kk.z); a1 += qreg[8 * i + 5] * bfhi(kk.z);
                    a2 += qreg[8 * i + 6] * bflo(kk.w); a3 += qreg[8 * i + 7] * bfhi(kk.w);
                }
            }
            s = (a0 + a1) + (a2 + a3);
            s += __shfl_xor(s, 1, 64);       // 4-lane butterfly -> full dot in all 4 lanes
            s += __shfl_xor(s, 2, 64);
        }
        if (sub == 0) lds_w[wave][k * CC + g] = s;
    }
    __syncthreads();

    // ---- softmax over the wave's pairs (self pair j==n always valid) ----
    // pair idx pp = k*CC + c  ->  c = pp & 15 (since CC == 16, 64 % 16 == 0)
    float s0 = (lane < nb) ? lds_w[wave][lane] : NEG_BIG;
    float s1 = (nb > 64 && lane + 64 < nb) ? lds_w[wave][lane + 64] : NEG_BIG;
    float m = fmaxf(s0, s1);
    #pragma unroll
    for (int mm = 32; mm >= 1; mm >>= 1) m = fmaxf(m, __shfl_xor(m, mm, 64));
    float e0 = (s0 <= NEG_BIG) ? 0.f : expf(s0 - m);
    float e1 = (s1 <= NEG_BIG) ? 0.f : expf(s1 - m);
    float tsum = e0 + e1;
    #pragma unroll
    for (int mm = 32; mm >= 1; mm >>= 1) tsum += __shfl_xor(tsum, mm, 64);
    float inv = 1.0f / tsum;
    float gv  = gate[b * CC + (lane & 15)];  // 2KB array, L2-hot broadcast
    lds_w[wave][lane] = e0 * inv * gv;       // gate folded into weight
    if (nb > 64 && lane + 64 < nb)
        lds_w[wave][lane + 64] = e1 * inv * gv;
    __syncthreads();

    // ---- output: lane e accumulates over valid pairs (coalesced V reads) ----
    float acc0 = 0.f, acc1 = 0.f;
    for (int k = 0; k < K; ++k) {
        int j = n + (k - (K >> 1)) * dil;
        if (j < 0 || j >= NN) continue;      // wave-uniform skip
        const float* wrow = lds_w[wave] + k * CC;
        const size_t base = kvoff + (size_t)j * DD + lane;
        #pragma unroll
        for (int c = 0; c < CC; c += 2) {
            float w0 = wrow[c], w1 = wrow[c + 1];
            size_t o0 = base + (size_t)c * (NN * DD);
            size_t o1 = o0 + (size_t)(NN * DD);
            float v0 = F32 ? ((const float*)vptr)[o0] : bf2f(((const unsigned short*)vptr)[o0]);
            float v1 = F32 ? ((const float*)vptr)[o1] : bf2f(((const unsigned short*)vptr)[o1]);
            acc0 += w0 * v0;
            acc1 += w1 * v1;
        }
    }
    float acc = acc0 + acc1;
    if constexpr (F32) ((float*)optr)[qoff + lane] = acc;
    else               ((unsigned short*)optr)[qoff + lane] = f2bf(acc);
}

extern "C" void kernel_launch(void* const* d_in, const int* in_sizes, int n_in,
                              void* d_out, int out_size, void* d_ws, size_t ws_size,
                              hipStream_t stream) {
    const void* queries = d_in[0];
    const void* keys    = d_in[1];
    const void* values  = d_in[2];
    const void* w1      = d_in[3];
    const void* b1      = d_in[4];
    const void* w2      = d_in[5];
    const void* b2      = d_in[6];
    // d_in[7] = na_mask: unused — neighborhood structure is regenerated analytically

    int*   flag    = (int*)d_ws;                    // 1 int
    float* gate_ws = (float*)d_ws + 64;             // B*C floats, offset 256 B

    hipLaunchKernelGGL(detect_dtype, dim3(1), dim3(64), 0, stream,
                       (const unsigned short*)queries, flag);
    hipLaunchKernelGGL((gate_kernel<false>), dim3(BB * CC), dim3(256), 0, stream,
                       values, w1, b1, w2, b2, flag, gate_ws);
    hipLaunchKernelGGL((gate_kernel<true>), dim3(BB * CC), dim3(256), 0, stream,
                       values, w1, b1, w2, b2, flag, gate_ws);
    hipLaunchKernelGGL((attn_kernel<false>), dim3(BB * HH * NN / 4), dim3(256), 0, stream,
                       queries, keys, values, gate_ws, flag, d_out);
    hipLaunchKernelGGL((attn_kernel<true>), dim3(BB * HH * NN / 4), dim3(256), 0, stream,
                       queries, keys, values, gate_ws, flag, d_out);
}